// Round 4
// baseline (43.634 us; speedup 1.0000x reference)
//
#include <hip/hip_runtime.h>
#include <math.h>

#define EDGE_DIM 3
#define NUM_HEADS 8
#define HIDDEN 16

typedef float float4v __attribute__((ext_vector_type(4)));

// Per-edge tiny MLP: (3) -> (16) relu -> (8)
__device__ __forceinline__ void edge_mlp(const float a0, const float a1, const float a2,
                                         const float* __restrict__ W1,
                                         const float* __restrict__ b1,
                                         const float* __restrict__ W2,
                                         const float* __restrict__ b2,
                                         float* o /* [NUM_HEADS] */) {
    float h[HIDDEN];
#pragma unroll
    for (int j = 0; j < HIDDEN; ++j) {
        float s = b1[j];
        s += a0 * W1[0 * HIDDEN + j];
        s += a1 * W1[1 * HIDDEN + j];
        s += a2 * W1[2 * HIDDEN + j];
        h[j] = s > 0.0f ? s : 0.0f;
    }
#pragma unroll
    for (int i = 0; i < NUM_HEADS; ++i) {
        float s = b2[i];
#pragma unroll
        for (int j = 0; j < HIDDEN; ++j) s += h[j] * W2[j * NUM_HEADS + i];
        o[i] = s;
    }
}

// Pass 2: per edge — compute MLP into edge_bias table (2 MB, L2-resident) and
// mark the winner per (src,dst) slot via atomicMax(e+1) (matches JAX scatter
// last-write-wins: winner = max edge index). Marker table was zeroed.
__global__ void k_mark_mlp(const int* __restrict__ ei, const float* __restrict__ ea,
                           const float* __restrict__ W1, const float* __restrict__ b1,
                           const float* __restrict__ W2, const float* __restrict__ b2,
                           unsigned* __restrict__ marker, float4v* __restrict__ ebias,
                           int E, int N) {
    int e = blockIdx.x * blockDim.x + threadIdx.x;
    if (e >= E) return;
    float o[NUM_HEADS];
    edge_mlp(ea[e * EDGE_DIM + 0], ea[e * EDGE_DIM + 1], ea[e * EDGE_DIM + 2],
             W1, b1, W2, b2, o);
    float4v lo = {o[0], o[1], o[2], o[3]};
    float4v hi = {o[4], o[5], o[6], o[7]};
    ebias[(size_t)e * 2 + 0] = lo;
    ebias[(size_t)e * 2 + 1] = hi;
    int src = ei[e];
    int dst = ei[E + e];
    size_t slot = (size_t)src * (size_t)N + (size_t)dst;
    atomicMax(&marker[slot], (unsigned)(e + 1));
}

// Pass 3: slot-centric single-touch fill. One thread per (src,dst) slot:
// coalesced 4B marker read; write the 32B slot exactly once — zeros, or the
// winning edge's precomputed bias (32B gather from the L2-resident table).
// No RMW, no hazards, output written exactly once per call.
__global__ void k_fill(const unsigned* __restrict__ marker,
                       const float4v* __restrict__ ebias,
                       float4v* __restrict__ out, size_t nslots) {
    size_t s = (size_t)blockIdx.x * blockDim.x + threadIdx.x;
    if (s >= nslots) return;
    unsigned m = marker[s];
    float4v lo = {0.0f, 0.0f, 0.0f, 0.0f};
    float4v hi = {0.0f, 0.0f, 0.0f, 0.0f};
    if (m) {
        size_t e = (size_t)(m - 1);
        lo = ebias[e * 2 + 0];
        hi = ebias[e * 2 + 1];
    }
    out[s * 2 + 0] = lo;
    out[s * 2 + 1] = hi;
}

// ---- Fallback path (round-3 structure) if ws_size is too small ----
__global__ void k_mark_out(const int* __restrict__ ei, float* __restrict__ out,
                           int E, int N) {
    int e = blockIdx.x * blockDim.x + threadIdx.x;
    if (e >= E) return;
    size_t slot = (size_t)ei[e] * (size_t)N + (size_t)ei[E + e];
    atomicMax((unsigned*)(out + slot * NUM_HEADS), (unsigned)(e + 1));
}

__global__ void k_write_out(const int* __restrict__ ei, const float* __restrict__ ea,
                            const float* __restrict__ W1, const float* __restrict__ b1,
                            const float* __restrict__ W2, const float* __restrict__ b2,
                            float* __restrict__ out, int E, int N) {
    int e = blockIdx.x * blockDim.x + threadIdx.x;
    if (e >= E) return;
    size_t slot = (size_t)ei[e] * (size_t)N + (size_t)ei[E + e];
    float* p = out + slot * NUM_HEADS;
    unsigned m = *(const unsigned*)p;
    if (m != (unsigned)(e + 1)) return;
    float o[NUM_HEADS];
    edge_mlp(ea[e * EDGE_DIM + 0], ea[e * EDGE_DIM + 1], ea[e * EDGE_DIM + 2],
             W1, b1, W2, b2, o);
    unsigned u = __float_as_uint(o[0]);
    if (u >= 1u && u <= (unsigned)E) o[0] = 0.0f;
    float4v lo = {o[0], o[1], o[2], o[3]};
    float4v hi = {o[4], o[5], o[6], o[7]};
    *(float4v*)p = lo;
    *(float4v*)(p + 4) = hi;
}

extern "C" void kernel_launch(void* const* d_in, const int* in_sizes, int n_in,
                              void* d_out, int out_size, void* d_ws, size_t ws_size,
                              hipStream_t stream) {
    const int* ei   = (const int*)d_in[0];    // (2, E) int32
    const float* ea = (const float*)d_in[1];  // (E, 3) f32
    const float* W1 = (const float*)d_in[3];  // (3, 16)
    const float* b1 = (const float*)d_in[4];  // (16,)
    const float* W2 = (const float*)d_in[5];  // (16, 8)
    const float* b2 = (const float*)d_in[6];  // (8,)
    float* out = (float*)d_out;

    const int E = in_sizes[0] / 2;
    const int N = (int)(sqrt((double)(out_size / NUM_HEADS)) + 0.5);
    const size_t nslots = (size_t)N * (size_t)N;

    const size_t marker_bytes = nslots * sizeof(unsigned);          // 16 MB
    const size_t ebias_bytes  = (size_t)E * NUM_HEADS * sizeof(float);  // 2 MB
    const int blk = 256;
    const int egrid = (E + blk - 1) / blk;

    if (ws_size >= marker_bytes + ebias_bytes) {
        unsigned* marker = (unsigned*)d_ws;
        float4v* ebias = (float4v*)((char*)d_ws + marker_bytes);  // 32B-aligned (16MB offset)

        // Pass 1: zero only the 16 MB marker table (not the 134 MB output).
        hipMemsetAsync(marker, 0, marker_bytes, stream);
        // Pass 2: MLP + winner marking (E threads).
        k_mark_mlp<<<egrid, blk, 0, stream>>>(ei, ea, W1, b1, W2, b2,
                                              marker, ebias, E, N);
        // Pass 3: single-touch fill of the 134 MB output.
        const size_t sgrid = (nslots + blk - 1) / blk;
        k_fill<<<(int)sgrid, blk, 0, stream>>>(marker, ebias, (float4v*)out, nslots);
    } else {
        // Fallback: round-3 structure (marker in out word 0).
        hipMemsetAsync(d_out, 0, (size_t)out_size * sizeof(float), stream);
        k_mark_out<<<egrid, blk, 0, stream>>>(ei, out, E, N);
        k_write_out<<<egrid, blk, 0, stream>>>(ei, ea, W1, b1, W2, b2, out, E, N);
    }
}